// Round 3
// baseline (262.220 us; speedup 1.0000x reference)
//
#include <hip/hip_runtime.h>
#include <hip/hip_fp16.h>

#define B_ 4
#define S_ 2048
#define H_ 1024
#define M_ (B_ * S_)  // 8192 flattened rows of x / q / k / v

typedef _Float16 f16;
typedef _Float16 f16x8 __attribute__((ext_vector_type(8)));
typedef _Float16 f16x4 __attribute__((ext_vector_type(4)));
typedef float f32x4 __attribute__((ext_vector_type(4)));

typedef __attribute__((address_space(3))) unsigned int* lds_u32p;
typedef const __attribute__((address_space(1))) unsigned int* gbl_u32p;

// async global->LDS, 16B per lane; HW dest = wave-uniform base + lane*16,
// which matches passing per-lane (base + t*8 halfs) pointers.
__device__ __forceinline__ void stage16(const f16* g, f16* l) {
  __builtin_amdgcn_global_load_lds((gbl_u32p)g, (lds_u32p)l, 16, 0, 0);
}

// ---------------------------------------------------------------------------
// One launch: x (8192 blocks) then Wq/Wk/Wv (1024 blocks each) -> fp16 RNE.
__global__ __launch_bounds__(256) void downconvert_all(
    const float* __restrict__ x, const float* __restrict__ W0,
    const float* __restrict__ W1, const float* __restrict__ W2,
    f16* __restrict__ xh, f16* __restrict__ Wh) {
  const int b = blockIdx.x;
  const float* src;
  f16* dst;
  long i;
  if (b < M_ * H_ / 1024) {  // 8192 x-blocks
    src = x; dst = xh;
    i = (long)b * 256 + threadIdx.x;
  } else {
    const int wb = b - M_ * H_ / 1024;
    const int sel = wb >> 10;               // 1024 blocks per W
    src = sel == 0 ? W0 : (sel == 1 ? W1 : W2);
    dst = Wh + (long)sel * H_ * H_;
    i = (long)(wb & 1023) * 256 + threadIdx.x;
  }
  f32x4 v = ((const f32x4*)src)[i];
  f16x4 h;
#pragma unroll
  for (int c = 0; c < 4; c++) h[c] = (f16)v[c];
  ((f16x4*)dst)[i] = h;
}

// ---------------------------------------------------------------------------
// 128x128-tile NT fp16 GEMM, counted-vmcnt pipelined schedule.
//   - 256 threads = 4 waves (2M x 2N), per-wave 64x64 (acc 4x4 f32x4).
//   - BK=32, 3 LDS buffers (48 KiB total) -> 3 blocks/CU (12 waves) so
//     cross-block overlap hides the read-phase/MFMA-phase alternation.
//   - depth-2 prefetch: phase kt stages K-tile kt+2; s_waitcnt vmcnt(4)
//     (= skip the 4 in-flight loads of tile kt+1) + barrier guarantees
//     tile kt landed in LDS. vmcnt never drains to 0 in steady state.
//   - race safety: stage target buf (kt+2)%3 == (kt-1)%3; every wave's
//     reads of that buffer completed before bar1(kt), because arrival at
//     bar1(kt) implies MFMA(kt-1) issued, which implies lgkmcnt(0) drained.
//   - LDS buffer = 128 rows x 32 halfs = 4096 halfs. One 256-thread stage16
//     pass covers 2048 halfs (rows 0..63); second pass lands at +2048
//     (rows 64..127).  [r2 bug: this was +4096 -> cross-buffer corruption]
//   - LDS swizzle (bank-conflict-free, measured 0 in r1): 16B chunk c of
//     row r holds global chunk c ^ ((r>>1)&3); applied identically on the
//     global SOURCE of global_load_lds (LDS dest stays linear) and on the
//     ds_read address.
// EPI: 0 = f16 C with alpha (scores), 1 = f32 C (PV epilogue to d_out),
//      2 = qkv projection (bias add; sel==2 (V) written transposed to vT).
template <int KTOT, int EPI>
__global__ __launch_bounds__(256, 3)
void gemm_p(const f16* __restrict__ A, const f16* __restrict__ Bm,
            void* __restrict__ Cout, f16* __restrict__ vT,
            const float* __restrict__ bq, const float* __restrict__ bk,
            const float* __restrict__ bv,
            int lda, int ldb, int ldc, long sA, long sB, long sC,
            float alpha) {
  __shared__ __align__(16) f16 LA[3][128 * 32];
  __shared__ __align__(16) f16 LB[3][128 * 32];
  const int t = threadIdx.x;
  const int wave = t >> 6, lane = t & 63;
  const int quad = lane >> 4, l16 = lane & 15;
  const int wm = (wave & 1) * 64, wn = (wave >> 1) * 64;

  int sel = 0, ntile = 0, mtile = blockIdx.x * 128;
  const f16 *Ab, *Bb;
  if (EPI == 2) {
    sel = blockIdx.y >> 3;                   // 0=q 1=k 2=v
    ntile = (blockIdx.y & 7) * 128;
    Ab = A + (long)mtile * lda;
    Bb = Bm + (long)sel * H_ * H_ + (long)ntile * ldb;
  } else {
    ntile = blockIdx.y * 128;
    Ab = A + blockIdx.z * sA + (long)mtile * lda;
    Bb = Bm + blockIdx.z * sB + (long)ntile * ldb;
  }

  // staging: thread t covers rows srow and srow+64, 16B chunk (t&3);
  // source chunk pre-swizzled so linear LDS dest ends up swizzled.
  // ((srow+64)>>1)&3 == (srow>>1)&3, so one sch serves both halves.
  const int srow = t >> 2;
  const int sch = (t & 3) ^ ((srow >> 1) & 3);
  const long ga = (long)srow * lda + sch * 8;
  const long gb = (long)srow * ldb + sch * 8;

  // ds_read: fragment row = w? + i*16 + l16 -> (row>>1)&3 == (l16>>1)&3.
  const int swz8 = (quad ^ ((l16 >> 1) & 3)) * 8;
  const int aoff = (wm + l16) * 32 + swz8;
  const int boff = (wn + l16) * 32 + swz8;

  f32x4 acc[4][4] = {};

  // prologue: stage K-tiles 0 and 1 (4 loads each; tile-0's 4 issue first)
#pragma unroll
  for (int p = 0; p < 2; ++p) {
    stage16(Ab + ga + p * 32,                    &LA[p][t * 8]);
    stage16(Ab + ga + (long)64 * lda + p * 32,   &LA[p][t * 8 + 2048]);
    stage16(Bb + gb + p * 32,                    &LB[p][t * 8]);
    stage16(Bb + gb + (long)64 * ldb + p * 32,   &LB[p][t * 8 + 2048]);
  }

  constexpr int NT = KTOT / 32;
  int rb = 0, sb = 2;   // read buffer, stage buffer ((kt+2)%3)
  long kg = 64;         // element k-offset of the tile being staged

#pragma unroll 3
  for (int kt = 0; kt < NT - 2; ++kt) {
    asm volatile("s_waitcnt vmcnt(4)" ::: "memory");
    __builtin_amdgcn_s_barrier();
    const f16* LAb = &LA[rb][0];
    const f16* LBb = &LB[rb][0];
    f16x8 af[4], bf[4];
#pragma unroll
    for (int i = 0; i < 4; ++i) {
      af[i] = *(const f16x8*)&LAb[aoff + i * 512];
      bf[i] = *(const f16x8*)&LBb[boff + i * 512];
    }
    f16* sa = &LA[sb][0];
    f16* sbb = &LB[sb][0];
    stage16(Ab + ga + kg,                  sa + t * 8);
    stage16(Ab + ga + (long)64 * lda + kg, sa + t * 8 + 2048);
    stage16(Bb + gb + kg,                  sbb + t * 8);
    stage16(Bb + gb + (long)64 * ldb + kg, sbb + t * 8 + 2048);
    __builtin_amdgcn_s_barrier();
    asm volatile("s_waitcnt lgkmcnt(0)" ::: "memory");
    __builtin_amdgcn_sched_barrier(0);
    __builtin_amdgcn_s_setprio(1);
#pragma unroll
    for (int i = 0; i < 4; ++i)
#pragma unroll
      for (int j = 0; j < 4; ++j)
        acc[i][j] = __builtin_amdgcn_mfma_f32_16x16x32_f16(af[i], bf[j],
                                                           acc[i][j], 0, 0, 0);
    __builtin_amdgcn_s_setprio(0);
    kg += 32;
    rb = rb == 2 ? 0 : rb + 1;
    sb = sb == 2 ? 0 : sb + 1;
  }

  // tail phases: NT-2 (wait its 4 loads; tile NT-1 still in flight), NT-1.
#pragma unroll
  for (int tp = 0; tp < 2; ++tp) {
    if (tp == 0)
      asm volatile("s_waitcnt vmcnt(4)" ::: "memory");
    else
      asm volatile("s_waitcnt vmcnt(0)" ::: "memory");
    __builtin_amdgcn_s_barrier();
    const f16* LAb = &LA[rb][0];
    const f16* LBb = &LB[rb][0];
    f16x8 af[4], bf[4];
#pragma unroll
    for (int i = 0; i < 4; ++i) {
      af[i] = *(const f16x8*)&LAb[aoff + i * 512];
      bf[i] = *(const f16x8*)&LBb[boff + i * 512];
    }
    __builtin_amdgcn_s_barrier();
    asm volatile("s_waitcnt lgkmcnt(0)" ::: "memory");
    __builtin_amdgcn_sched_barrier(0);
    __builtin_amdgcn_s_setprio(1);
#pragma unroll
    for (int i = 0; i < 4; ++i)
#pragma unroll
      for (int j = 0; j < 4; ++j)
        acc[i][j] = __builtin_amdgcn_mfma_f32_16x16x32_f16(af[i], bf[j],
                                                           acc[i][j], 0, 0, 0);
    __builtin_amdgcn_s_setprio(0);
    rb = rb == 2 ? 0 : rb + 1;
  }

  // ---- epilogue ----
  if (EPI == 0) {
    f16* C = (f16*)Cout + blockIdx.z * sC;
#pragma unroll
    for (int i = 0; i < 4; ++i)
#pragma unroll
      for (int j = 0; j < 4; ++j) {
        const long m = mtile + wm + i * 16 + quad * 4;
        const long n = ntile + wn + j * 16 + l16;
#pragma unroll
        for (int r = 0; r < 4; ++r)
          C[(m + r) * ldc + n] = (f16)(acc[i][j][r] * alpha);
      }
  } else if (EPI == 1) {
    float* C = (float*)Cout + blockIdx.z * sC;
#pragma unroll
    for (int i = 0; i < 4; ++i)
#pragma unroll
      for (int j = 0; j < 4; ++j) {
        const long m = mtile + wm + i * 16 + quad * 4;
        const long n = ntile + wn + j * 16 + l16;
#pragma unroll
        for (int r = 0; r < 4; ++r)
          C[(m + r) * ldc + n] = acc[i][j][r] * alpha;
      }
  } else {
    const float* bias = sel == 0 ? bq : (sel == 1 ? bk : bv);
    if (sel == 2) {
      // V transposed: vT[(b*H + n)*S + t_pos], b = m>>11, t_pos = m&2047.
#pragma unroll
      for (int j = 0; j < 4; ++j) {
        const int n = ntile + wn + j * 16 + l16;
        const float bb = bias[n];
#pragma unroll
        for (int i = 0; i < 4; ++i) {
          const int m = mtile + wm + i * 16 + quad * 4;
          f16x4 pack;
#pragma unroll
          for (int r = 0; r < 4; ++r) pack[r] = (f16)(acc[i][j][r] + bb);
          *(f16x4*)&vT[((long)(m >> 11) * H_ + n) * S_ + (m & 2047)] = pack;
        }
      }
    } else {
      f16* C = (f16*)Cout + (long)sel * M_ * H_;
#pragma unroll
      for (int j = 0; j < 4; ++j) {
        const int n = ntile + wn + j * 16 + l16;
        const float bb = bias[n];
#pragma unroll
        for (int i = 0; i < 4; ++i) {
          const long m = mtile + wm + i * 16 + quad * 4;
#pragma unroll
          for (int r = 0; r < 4; ++r)
            C[(m + r) * ldc + n] = (f16)(acc[i][j][r] + bb);
        }
      }
    }
  }
}

// ---------------------------------------------------------------------------
// In-place row softmax over 2048 fp16 scores + quantize to fp16.
__global__ __launch_bounds__(256) void softmax_q(f16* __restrict__ sc) {
  const long row = blockIdx.x;
  f16* p = sc + row * S_;
  const int t = threadIdx.x;
  const int wave = t >> 6, lane = t & 63;
  f16x8 v = ((const f16x8*)p)[t];
  float f[8];
  float m = -3.0e38f;
#pragma unroll
  for (int c = 0; c < 8; c++) { f[c] = (float)v[c]; m = fmaxf(m, f[c]); }
#pragma unroll
  for (int o = 32; o > 0; o >>= 1) m = fmaxf(m, __shfl_xor(m, o));
  __shared__ float redm[4], reds[4];
  if (lane == 0) redm[wave] = m;
  __syncthreads();
  m = fmaxf(fmaxf(redm[0], redm[1]), fmaxf(redm[2], redm[3]));
  float s = 0.f, e[8];
#pragma unroll
  for (int c = 0; c < 8; c++) { e[c] = __expf(f[c] - m); s += e[c]; }
#pragma unroll
  for (int o = 32; o > 0; o >>= 1) s += __shfl_xor(s, o);
  if (lane == 0) reds[wave] = s;
  __syncthreads();
  s = reds[0] + reds[1] + reds[2] + reds[3];
  float inv = 1.0f / s;
  f16x8 ov;
#pragma unroll
  for (int c = 0; c < 8; c++) ov[c] = (f16)(e[c] * inv);
  ((f16x8*)p)[t] = ov;
}

// ---------------------------------------------------------------------------
extern "C" void kernel_launch(void* const* d_in, const int* in_sizes, int n_in,
                              void* d_out, int out_size, void* d_ws, size_t ws_size,
                              hipStream_t stream) {
  (void)in_sizes; (void)n_in; (void)out_size; (void)ws_size;
  const float* x  = (const float*)d_in[0];
  const float* Wq = (const float*)d_in[1];
  const float* bq = (const float*)d_in[2];
  const float* Wk = (const float*)d_in[3];
  const float* bk = (const float*)d_in[4];
  const float* Wv = (const float*)d_in[5];
  const float* bv = (const float*)d_in[6];

  char* ws = (char*)d_ws;
  f16* xh  = (f16*)ws; ws += (size_t)M_ * H_ * 2;          // 16 MiB
  f16* Wh  = (f16*)ws; ws += (size_t)3 * H_ * H_ * 2;      // 6 MiB
  f16* qkv = (f16*)ws; ws += (size_t)2 * M_ * H_ * 2;      // 32 MiB (q, k)
  f16* vT  = (f16*)ws; ws += (size_t)B_ * H_ * S_ * 2;     // 16 MiB
  f16* sc  = (f16*)ws; ws += (size_t)B_ * S_ * S_ * 2;     // 32 MiB (scores, then attn in-place)

  // 1) x, Wq/Wk/Wv -> fp16 in one launch
  downconvert_all<<<M_ * H_ / 1024 + 3 * H_ * H_ / 1024, 256, 0, stream>>>(
      x, Wq, Wk, Wv, xh, Wh);

  // 2) fused QKV projection + bias + quantize; V written transposed.
  //    grid 64 x 24 = 1536 blocks, 3/CU -> exactly 2 residency rounds.
  gemm_p<1024, 2><<<dim3(64, 24), 256, 0, stream>>>(
      xh, Wh, qkv, vT, bq, bk, bv, H_, H_, H_, 0, 0, 0, 0.f);

  // 3) scores = quantize(q @ k^T / 32): grid 16 x 16 x 4 = 1024 blocks.
  gemm_p<1024, 0><<<dim3(16, 16, 4), 256, 0, stream>>>(
      qkv, qkv + (size_t)M_ * H_, sc, nullptr, nullptr, nullptr, nullptr,
      H_, H_, S_, (long)S_ * H_, (long)S_ * H_, (long)S_ * S_, 0.03125f);

  // 4) attn = quantize(softmax(scores)) in-place
  softmax_q<<<M_, 256, 0, stream>>>(sc);

  // 5) out = attn @ vT^T (fp32 straight to d_out): grid 16 x 8 x 4 = 512.
  gemm_p<2048, 1><<<dim3(16, 8, 4), 256, 0, stream>>>(
      sc, vT, d_out, nullptr, nullptr, nullptr, nullptr,
      S_, S_, H_, (long)S_ * S_, (long)H_ * S_, (long)S_ * H_, 1.0f);
}

// Round 4
// 256.165 us; speedup vs baseline: 1.0236x; 1.0236x over previous
//
#include <hip/hip_runtime.h>
#include <hip/hip_fp16.h>

#define B_ 4
#define S_ 2048
#define H_ 1024
#define M_ (B_ * S_)  // 8192 flattened rows of x / q / k / v

typedef _Float16 f16;
typedef _Float16 f16x8 __attribute__((ext_vector_type(8)));
typedef _Float16 f16x4 __attribute__((ext_vector_type(4)));
typedef float f32x4 __attribute__((ext_vector_type(4)));

typedef __attribute__((address_space(3))) unsigned int* lds_u32p;
typedef const __attribute__((address_space(1))) unsigned int* gbl_u32p;

// async global->LDS, 16B per lane; HW dest = wave-uniform base + lane*16,
// which matches passing per-lane (base + t*8 halfs) pointers.
__device__ __forceinline__ void stage16(const f16* g, f16* l) {
  __builtin_amdgcn_global_load_lds((gbl_u32p)g, (lds_u32p)l, 16, 0, 0);
}

// ---------------------------------------------------------------------------
// One launch: x (8192 blocks) then Wq/Wk/Wv (1024 blocks each) -> fp16 RNE.
__global__ __launch_bounds__(256) void downconvert_all(
    const float* __restrict__ x, const float* __restrict__ W0,
    const float* __restrict__ W1, const float* __restrict__ W2,
    f16* __restrict__ xh, f16* __restrict__ Wh) {
  const int b = blockIdx.x;
  const float* src;
  f16* dst;
  long i;
  if (b < M_ * H_ / 1024) {  // 8192 x-blocks
    src = x; dst = xh;
    i = (long)b * 256 + threadIdx.x;
  } else {
    const int wb = b - M_ * H_ / 1024;
    const int sel = wb >> 10;               // 1024 blocks per W
    src = sel == 0 ? W0 : (sel == 1 ? W1 : W2);
    dst = Wh + (long)sel * H_ * H_;
    i = (long)(wb & 1023) * 256 + threadIdx.x;
  }
  f32x4 v = ((const f32x4*)src)[i];
  f16x4 h;
#pragma unroll
  for (int c = 0; c < 4; c++) h[c] = (f16)v[c];
  ((f16x4*)dst)[i] = h;
}

// ---------------------------------------------------------------------------
// FAT-WAVE 128x128-tile NT fp16 GEMM.
//   - 128 threads = 2 waves; each wave owns ALL 128 rows x 64 cols
//     (acc 8x4 f32x4 = 128 VGPR). 43.7 FLOP per LDS-read byte vs 32 for
//     the 64x64 wave tile -> LDS-read pipe off the critical path.
//   - 4 blocks/CU (LDS 32KB, VGPR ~220 -> 2 waves/SIMD): 4 INDEPENDENT
//     2-wave barrier groups per CU overlap each other's stage-drain
//     stalls (m114 mechanism; r0 had only ~2.4 correlated 4-wave groups).
//   - Staging/barrier structure identical to the proven r0 loop: BK=64 as
//     two [128][32] sub-chunks, plain __syncthreads (full drain) -- the
//     r1/r3 counted-vmcnt variants measured WORSE (76/71 vs 61 us).
//   - chunk-XOR swizzle (verified 0 bank conflicts in r1/r3): 16B chunk c
//     of row r holds global chunk c ^ ((r>>1)&3); applied on the global
//     source of stage16 (LDS dest linear) and on the ds_read address.
// EPI: 0 = f16 C with alpha (scores), 2 = qkv projection (bias add;
//      sel==2 (V) written transposed to vT).
template <int KTOT, int EPI>
__global__ __launch_bounds__(128, 2)
void gemm_f(const f16* __restrict__ A, const f16* __restrict__ Bm,
            void* __restrict__ Cout, f16* __restrict__ vT,
            const float* __restrict__ bq, const float* __restrict__ bk,
            const float* __restrict__ bv,
            int lda, int ldb, int ldc, long sA, long sB, long sC,
            float alpha) {
  __shared__ __align__(16) f16 As[2][128 * 32];
  __shared__ __align__(16) f16 Bs[2][128 * 32];
  const int t = threadIdx.x;            // 0..127
  const int wave = t >> 6, lane = t & 63;
  const int quad = lane >> 4, l16 = lane & 15;
  const int wn = wave * 64;

  int sel = 0, ntile = 0, mtile = blockIdx.x * 128;
  const f16 *Ab, *Bb;
  if (EPI == 2) {
    sel = blockIdx.y >> 3;                   // 0=q 1=k 2=v
    ntile = (blockIdx.y & 7) * 128;
    Ab = A + (long)mtile * lda;
    Bb = Bm + (long)sel * H_ * H_ + (long)ntile * ldb;
  } else {
    ntile = blockIdx.y * 128;
    Ab = A + blockIdx.z * sA + (long)mtile * lda;
    Bb = Bm + blockIdx.z * sB + (long)ntile * ldb;
  }

  // staging map: pass j covers rows 32j..32j+31 of a [128][32] sub-chunk;
  // thread t -> row 32j + (t>>2), dest chunk (t&3), source chunk swizzled.
  // ((32j + (t>>2))>>1)&3 == (t>>3)&3 for all j (32j>>1 = 16j, &3 == 0).
  const int srow = t >> 2;
  const int sch = (t & 3) ^ ((t >> 3) & 3);
  const long gaBase = (long)srow * lda + sch * 8;
  const long gbBase = (long)srow * ldb + sch * 8;

  // ds_read: fragment row = mi*16 + l16 (A) / wn + ni*16 + l16 (B);
  // (row>>1)&3 == (l16>>1)&3 in both cases.
  const int swz8 = (quad ^ ((l16 >> 1) & 3)) * 8;
  const int aoff = l16 * 32 + swz8;          // + mi*512
  const int boff = (wn + l16) * 32 + swz8;   // + ni*512

  f32x4 acc[8][4] = {};

  for (int k0 = 0; k0 < KTOT; k0 += 64) {
    __syncthreads();
#pragma unroll
    for (int j = 0; j < 4; ++j) {
      const long rA = gaBase + (long)(32 * j) * lda + k0;
      const long rB = gbBase + (long)(32 * j) * ldb + k0;
      stage16(Ab + rA,      &As[0][j * 1024 + t * 8]);
      stage16(Ab + rA + 32, &As[1][j * 1024 + t * 8]);
      stage16(Bb + rB,      &Bs[0][j * 1024 + t * 8]);
      stage16(Bb + rB + 32, &Bs[1][j * 1024 + t * 8]);
    }
    __syncthreads();
#pragma unroll
    for (int kk = 0; kk < 2; ++kk) {
      f16x8 af[4], bf[4];
#pragma unroll
      for (int i = 0; i < 4; ++i) {
        af[i] = *(const f16x8*)&As[kk][aoff + i * 512];
        bf[i] = *(const f16x8*)&Bs[kk][boff + i * 512];
      }
#pragma unroll
      for (int i = 0; i < 4; ++i)
#pragma unroll
        for (int j2 = 0; j2 < 4; ++j2)
          acc[i][j2] = __builtin_amdgcn_mfma_f32_16x16x32_f16(
              af[i], bf[j2], acc[i][j2], 0, 0, 0);
      f16x8 ag[4];
#pragma unroll
      for (int i = 0; i < 4; ++i)
        ag[i] = *(const f16x8*)&As[kk][aoff + (i + 4) * 512];
#pragma unroll
      for (int i = 0; i < 4; ++i)
#pragma unroll
        for (int j2 = 0; j2 < 4; ++j2)
          acc[i + 4][j2] = __builtin_amdgcn_mfma_f32_16x16x32_f16(
              ag[i], bf[j2], acc[i + 4][j2], 0, 0, 0);
    }
  }

  // ---- epilogue: m = mtile + mi*16 + quad*4 (mi 0..7), n = ntile+wn+ni*16+l16
  if (EPI == 0) {
    f16* C = (f16*)Cout + blockIdx.z * sC;
#pragma unroll
    for (int mi = 0; mi < 8; ++mi)
#pragma unroll
      for (int ni = 0; ni < 4; ++ni) {
        const long m = mtile + mi * 16 + quad * 4;
        const long n = ntile + wn + ni * 16 + l16;
#pragma unroll
        for (int r = 0; r < 4; ++r)
          C[(m + r) * ldc + n] = (f16)(acc[mi][ni][r] * alpha);
      }
  } else {
    const float* bias = sel == 0 ? bq : (sel == 1 ? bk : bv);
    if (sel == 2) {
      // V transposed: vT[(b*H + n)*S + t_pos], b = m>>11, t_pos = m&2047.
#pragma unroll
      for (int ni = 0; ni < 4; ++ni) {
        const int n = ntile + wn + ni * 16 + l16;
        const float bb = bias[n];
#pragma unroll
        for (int mi = 0; mi < 8; ++mi) {
          const int m = mtile + mi * 16 + quad * 4;
          f16x4 pack;
#pragma unroll
          for (int r = 0; r < 4; ++r) pack[r] = (f16)(acc[mi][ni][r] + bb);
          *(f16x4*)&vT[((long)(m >> 11) * H_ + n) * S_ + (m & 2047)] = pack;
        }
      }
    } else {
      f16* C = (f16*)Cout + (long)sel * M_ * H_;
#pragma unroll
      for (int ni = 0; ni < 4; ++ni) {
        const int n = ntile + wn + ni * 16 + l16;
        const float bb = bias[n];
#pragma unroll
        for (int mi = 0; mi < 8; ++mi) {
          const long m = mtile + mi * 16 + quad * 4;
#pragma unroll
          for (int r = 0; r < 4; ++r)
            C[(m + r) * ldc + n] = (f16)(acc[mi][ni][r] + bb);
        }
      }
    }
  }
}

// ---------------------------------------------------------------------------
// r0-proven generic batched NT fp16 GEMM (128x128, 4 waves, BK=64) for PV
// (512 blocks of 256 threads fill the machine; a 128-thread grid would not).
template <int OUT_F16>
__global__ __launch_bounds__(256, 2)
void gemm_nt(const f16* __restrict__ A, const f16* __restrict__ Bm,
             void* __restrict__ C, int lda, int ldb, int ldc, int K,
             long sA, long sB, long sC, float alpha) {
  __shared__ __align__(16) f16 As[2 * 128 * 32];
  __shared__ __align__(16) f16 Bs[2 * 128 * 32];
  const int t = threadIdx.x;
  const int wave = t >> 6, lane = t & 63;
  const int quad = lane >> 4, l16 = lane & 15;
  const int wm = (wave & 1) * 64, wn = (wave >> 1) * 64;
  const f16* Ab = A + blockIdx.z * sA + (long)blockIdx.x * 128 * lda;
  const f16* Bb = Bm + blockIdx.z * sB + (long)blockIdx.y * 128 * ldb;
  const int r0 = t >> 2, c8 = (t & 3) * 8;
  f32x4 acc[4][4] = {};
  for (int k0 = 0; k0 < K; k0 += 64) {
    __syncthreads();
    stage16(Ab + (long)r0 * lda + k0 + c8,             As + t * 8);
    stage16(Ab + (long)(r0 + 64) * lda + k0 + c8,      As + 2048 + t * 8);
    stage16(Ab + (long)r0 * lda + k0 + 32 + c8,        As + 4096 + t * 8);
    stage16(Ab + (long)(r0 + 64) * lda + k0 + 32 + c8, As + 6144 + t * 8);
    stage16(Bb + (long)r0 * ldb + k0 + c8,             Bs + t * 8);
    stage16(Bb + (long)(r0 + 64) * ldb + k0 + c8,      Bs + 2048 + t * 8);
    stage16(Bb + (long)r0 * ldb + k0 + 32 + c8,        Bs + 4096 + t * 8);
    stage16(Bb + (long)(r0 + 64) * ldb + k0 + 32 + c8, Bs + 6144 + t * 8);
    __syncthreads();
#pragma unroll
    for (int kk = 0; kk < 2; kk++) {
      f16x8 af[4], bf[4];
#pragma unroll
      for (int i = 0; i < 4; i++) {
        af[i] = *(const f16x8*)&As[kk * 4096 + (wm + i * 16 + l16) * 32 + quad * 8];
        bf[i] = *(const f16x8*)&Bs[kk * 4096 + (wn + i * 16 + l16) * 32 + quad * 8];
      }
#pragma unroll
      for (int i = 0; i < 4; i++)
#pragma unroll
        for (int j = 0; j < 4; j++)
          acc[i][j] = __builtin_amdgcn_mfma_f32_16x16x32_f16(af[i], bf[j], acc[i][j], 0, 0, 0);
    }
  }
  const long mb = (long)blockIdx.x * 128 + wm;
  const long nb = (long)blockIdx.y * 128 + wn;
#pragma unroll
  for (int i = 0; i < 4; i++)
#pragma unroll
    for (int j = 0; j < 4; j++) {
      long m = mb + i * 16 + quad * 4;
      long n = nb + j * 16 + l16;
#pragma unroll
      for (int r = 0; r < 4; r++) {
        float v = acc[i][j][r] * alpha;
        if (OUT_F16)
          ((f16*)C)[blockIdx.z * sC + (m + r) * ldc + n] = (f16)v;
        else
          ((float*)C)[blockIdx.z * sC + (m + r) * ldc + n] = v;
      }
    }
}

// ---------------------------------------------------------------------------
// In-place row softmax over 2048 fp16 scores + quantize to fp16.
__global__ __launch_bounds__(256) void softmax_q(f16* __restrict__ sc) {
  const long row = blockIdx.x;
  f16* p = sc + row * S_;
  const int t = threadIdx.x;
  const int wave = t >> 6, lane = t & 63;
  f16x8 v = ((const f16x8*)p)[t];
  float f[8];
  float m = -3.0e38f;
#pragma unroll
  for (int c = 0; c < 8; c++) { f[c] = (float)v[c]; m = fmaxf(m, f[c]); }
#pragma unroll
  for (int o = 32; o > 0; o >>= 1) m = fmaxf(m, __shfl_xor(m, o));
  __shared__ float redm[4], reds[4];
  if (lane == 0) redm[wave] = m;
  __syncthreads();
  m = fmaxf(fmaxf(redm[0], redm[1]), fmaxf(redm[2], redm[3]));
  float s = 0.f, e[8];
#pragma unroll
  for (int c = 0; c < 8; c++) { e[c] = __expf(f[c] - m); s += e[c]; }
#pragma unroll
  for (int o = 32; o > 0; o >>= 1) s += __shfl_xor(s, o);
  if (lane == 0) reds[wave] = s;
  __syncthreads();
  s = reds[0] + reds[1] + reds[2] + reds[3];
  float inv = 1.0f / s;
  f16x8 ov;
#pragma unroll
  for (int c = 0; c < 8; c++) ov[c] = (f16)(e[c] * inv);
  ((f16x8*)p)[t] = ov;
}

// ---------------------------------------------------------------------------
extern "C" void kernel_launch(void* const* d_in, const int* in_sizes, int n_in,
                              void* d_out, int out_size, void* d_ws, size_t ws_size,
                              hipStream_t stream) {
  (void)in_sizes; (void)n_in; (void)out_size; (void)ws_size;
  const float* x  = (const float*)d_in[0];
  const float* Wq = (const float*)d_in[1];
  const float* bq = (const float*)d_in[2];
  const float* Wk = (const float*)d_in[3];
  const float* bk = (const float*)d_in[4];
  const float* Wv = (const float*)d_in[5];
  const float* bv = (const float*)d_in[6];

  char* ws = (char*)d_ws;
  f16* xh  = (f16*)ws; ws += (size_t)M_ * H_ * 2;          // 16 MiB
  f16* Wh  = (f16*)ws; ws += (size_t)3 * H_ * H_ * 2;      // 6 MiB
  f16* qkv = (f16*)ws; ws += (size_t)2 * M_ * H_ * 2;      // 32 MiB (q, k)
  f16* vT  = (f16*)ws; ws += (size_t)B_ * H_ * S_ * 2;     // 16 MiB
  f16* sc  = (f16*)ws; ws += (size_t)B_ * S_ * S_ * 2;     // 32 MiB (scores, then attn in-place)

  // 1) x, Wq/Wk/Wv -> fp16 in one launch
  downconvert_all<<<M_ * H_ / 1024 + 3 * H_ * H_ / 1024, 256, 0, stream>>>(
      x, Wq, Wk, Wv, xh, Wh);

  // 2) fused QKV projection + bias + quantize; V written transposed.
  //    fat-wave kernel: grid 64 x 24 = 1536 blocks of 128 threads (4/CU).
  gemm_f<1024, 2><<<dim3(64, 24), 128, 0, stream>>>(
      xh, Wh, qkv, vT, bq, bk, bv, H_, H_, H_, 0, 0, 0, 0.f);

  // 3) scores = quantize(q @ k^T / 32): grid 16 x 16 x 4 = 1024 blocks
  //    of 128 threads = EXACTLY one residency round at 4 blocks/CU.
  gemm_f<1024, 0><<<dim3(16, 16, 4), 128, 0, stream>>>(
      qkv, qkv + (size_t)M_ * H_, sc, nullptr, nullptr, nullptr, nullptr,
      H_, H_, S_, (long)S_ * H_, (long)S_ * H_, (long)S_ * S_, 0.03125f);

  // 4) attn = quantize(softmax(scores)) in-place
  softmax_q<<<M_, 256, 0, stream>>>(sc);

  // 5) out = attn @ vT^T (fp32 straight to d_out): r0-proven kernel,
  //    grid 16 x 8 x 4 = 512 blocks of 256 threads.
  gemm_nt<0><<<dim3(16, 8, 4), 256, 0, stream>>>(
      sc, vT, d_out, S_, S_, H_, S_,
      (long)S_ * S_, (long)H_ * S_, (long)S_ * H_, 1.0f);
}

// Round 5
// 253.158 us; speedup vs baseline: 1.0358x; 1.0119x over previous
//
#include <hip/hip_runtime.h>
#include <hip/hip_fp16.h>

#define B_ 4
#define S_ 2048
#define H_ 1024
#define M_ (B_ * S_)  // 8192 flattened rows of x / q / k / v

typedef _Float16 f16;
typedef _Float16 f16x8 __attribute__((ext_vector_type(8)));
typedef _Float16 f16x4 __attribute__((ext_vector_type(4)));
typedef float f32x4 __attribute__((ext_vector_type(4)));

typedef __attribute__((address_space(3))) unsigned int* lds_u32p;
typedef const __attribute__((address_space(1))) unsigned int* gbl_u32p;

// async global->LDS, 16B per lane; HW dest = wave-uniform base + lane*16,
// which matches passing per-lane (base + t*8 halfs) pointers.
__device__ __forceinline__ void stage16(const f16* g, f16* l) {
  __builtin_amdgcn_global_load_lds((gbl_u32p)g, (lds_u32p)l, 16, 0, 0);
}

// ---------------------------------------------------------------------------
// One launch: x (8192 blocks) then Wq/Wk/Wv (1024 blocks each) -> fp16 RNE.
__global__ __launch_bounds__(256) void downconvert_all(
    const float* __restrict__ x, const float* __restrict__ W0,
    const float* __restrict__ W1, const float* __restrict__ W2,
    f16* __restrict__ xh, f16* __restrict__ Wh) {
  const int b = blockIdx.x;
  const float* src;
  f16* dst;
  long i;
  if (b < M_ * H_ / 1024) {  // 8192 x-blocks
    src = x; dst = xh;
    i = (long)b * 256 + threadIdx.x;
  } else {
    const int wb = b - M_ * H_ / 1024;
    const int sel = wb >> 10;               // 1024 blocks per W
    src = sel == 0 ? W0 : (sel == 1 ? W1 : W2);
    dst = Wh + (long)sel * H_ * H_;
    i = (long)(wb & 1023) * 256 + threadIdx.x;
  }
  f32x4 v = ((const f32x4*)src)[i];
  f16x4 h;
#pragma unroll
  for (int c = 0; c < 4; c++) h[c] = (f16)v[c];
  ((f16x4*)dst)[i] = h;
}

// ---------------------------------------------------------------------------
// 128x128-tile NT fp16 GEMM — r0 economics with ISSUE-EARLY / WAIT-LATE dbuf.
//   - 256 threads = 4 waves (2M x 2N), per-wave 64x64 (acc 4x4 f32x4) — r0.
//   - BK=64 as two [128][32] kk sub-chunks — r0.
//   - TRUE double buffer (2 x 32KB = 64KB LDS, 2 blocks/CU): at the top of
//     K-tile kt: vmcnt(0)+barrier drains loads issued a FULL K-tile ago
//     (wait-late: they had the whole 32-MFMA window to land), then the 8
//     stage passes for kt+1 are issued immediately (issue-early), then the
//     two 16-MFMA clusters run. ONE barrier per K-tile (r0 had two), and
//     the drain is no longer back-to-back with the stage issue (r0's
//     structural stall).
//   - race safety: a wave reaching kt's top barrier has drained its own
//     ds_reads of buf[kt&1] (compiler lgkmcnt before its MFMAs), so the
//     stage writes to buf[kt&1] issued after the barrier cannot race;
//     vmcnt(0) before the barrier publishes all waves' LDS stage-writes.
//   - chunk-XOR swizzle (r3-verified correct, 0 bank conflicts): 16B chunk
//     c of row r holds global chunk c ^ ((r>>1)&3); applied on the global
//     source of stage16 (LDS dest stays linear) and on the ds_read address.
// EPI: 0 = f16 C with alpha (scores), 1 = f32 C (PV -> d_out),
//      2 = qkv projection (bias add; sel==2 (V) written transposed to vT).
template <int KTOT, int EPI>
__global__ __launch_bounds__(256, 2)
void gemm_d(const f16* __restrict__ A, const f16* __restrict__ Bm,
            void* __restrict__ Cout, f16* __restrict__ vT,
            const float* __restrict__ bq, const float* __restrict__ bk,
            const float* __restrict__ bv,
            int lda, int ldb, int ldc, long sA, long sB, long sC,
            float alpha) {
  __shared__ __align__(16) f16 As[2][2 * 128 * 32];  // [buf][kk*4096 + r*32 + c]
  __shared__ __align__(16) f16 Bs[2][2 * 128 * 32];
  const int t = threadIdx.x;
  const int wave = t >> 6, lane = t & 63;
  const int quad = lane >> 4, l16 = lane & 15;
  const int wm = (wave & 1) * 64, wn = (wave >> 1) * 64;

  int sel = 0, ntile = 0, mtile = blockIdx.x * 128;
  const f16 *Ab, *Bb;
  if (EPI == 2) {
    sel = blockIdx.y >> 3;                   // 0=q 1=k 2=v
    ntile = (blockIdx.y & 7) * 128;
    Ab = A + (long)mtile * lda;
    Bb = Bm + (long)sel * H_ * H_ + (long)ntile * ldb;
  } else {
    ntile = blockIdx.y * 128;
    Ab = A + blockIdx.z * sA + (long)mtile * lda;
    Bb = Bm + blockIdx.z * sB + (long)ntile * ldb;
  }

  // staging: thread t covers rows srow / srow+64, dest 16B chunk (t&3);
  // global source chunk pre-swizzled so the linear LDS dest is swizzled.
  // ((srow+64)>>1)&3 == (srow>>1)&3, so one sch serves both row halves.
  const int srow = t >> 2;
  const int sch = (t & 3) ^ ((srow >> 1) & 3);
  const long ga = (long)srow * lda + sch * 8;
  const long gb = (long)srow * ldb + sch * 8;

  // ds_read: fragment row = w? + i*16 + l16 -> (row>>1)&3 == (l16>>1)&3.
  const int swz8 = (quad ^ ((l16 >> 1) & 3)) * 8;
  const int aoff = (wm + l16) * 32 + swz8;   // + i*512 (+kk*4096)
  const int boff = (wn + l16) * 32 + swz8;

  f32x4 acc[4][4] = {};

#define STAGE_TILE(buf, k0)                                                  \
  {                                                                          \
    f16* sa_ = &As[buf][0];                                                  \
    f16* sb_ = &Bs[buf][0];                                                  \
    stage16(Ab + ga + (k0),                       sa_ + t * 8);              \
    stage16(Ab + ga + (long)64 * lda + (k0),      sa_ + t * 8 + 2048);       \
    stage16(Ab + ga + (k0) + 32,                  sa_ + t * 8 + 4096);       \
    stage16(Ab + ga + (long)64 * lda + (k0) + 32, sa_ + t * 8 + 6144);       \
    stage16(Bb + gb + (k0),                       sb_ + t * 8);              \
    stage16(Bb + gb + (long)64 * ldb + (k0),      sb_ + t * 8 + 2048);       \
    stage16(Bb + gb + (k0) + 32,                  sb_ + t * 8 + 4096);       \
    stage16(Bb + gb + (long)64 * ldb + (k0) + 32, sb_ + t * 8 + 6144);       \
  }

  // prologue: tile 0 -> buf 0
  STAGE_TILE(0, 0)

  constexpr int NT = KTOT / 64;
#pragma unroll 2
  for (int kt = 0; kt < NT; ++kt) {
    const int cb = kt & 1;
    asm volatile("s_waitcnt vmcnt(0)" ::: "memory");
    __builtin_amdgcn_s_barrier();
    if (kt + 1 < NT) {
      STAGE_TILE(cb ^ 1, (kt + 1) * 64)
    }
#pragma unroll
    for (int kk = 0; kk < 2; ++kk) {
      f16x8 af[4], bf[4];
#pragma unroll
      for (int i = 0; i < 4; ++i) {
        af[i] = *(const f16x8*)&As[cb][kk * 4096 + aoff + i * 512];
        bf[i] = *(const f16x8*)&Bs[cb][kk * 4096 + boff + i * 512];
      }
      __builtin_amdgcn_s_setprio(1);
#pragma unroll
      for (int i = 0; i < 4; ++i)
#pragma unroll
        for (int j = 0; j < 4; ++j)
          acc[i][j] = __builtin_amdgcn_mfma_f32_16x16x32_f16(af[i], bf[j],
                                                             acc[i][j], 0, 0, 0);
      __builtin_amdgcn_s_setprio(0);
    }
  }
#undef STAGE_TILE

  // ---- epilogue (verbatim from the r0/r3-verified kernels) ----
  if (EPI == 0) {
    f16* C = (f16*)Cout + blockIdx.z * sC;
#pragma unroll
    for (int i = 0; i < 4; ++i)
#pragma unroll
      for (int j = 0; j < 4; ++j) {
        const long m = mtile + wm + i * 16 + quad * 4;
        const long n = ntile + wn + j * 16 + l16;
#pragma unroll
        for (int r = 0; r < 4; ++r)
          C[(m + r) * ldc + n] = (f16)(acc[i][j][r] * alpha);
      }
  } else if (EPI == 1) {
    float* C = (float*)Cout + blockIdx.z * sC;
#pragma unroll
    for (int i = 0; i < 4; ++i)
#pragma unroll
      for (int j = 0; j < 4; ++j) {
        const long m = mtile + wm + i * 16 + quad * 4;
        const long n = ntile + wn + j * 16 + l16;
#pragma unroll
        for (int r = 0; r < 4; ++r)
          C[(m + r) * ldc + n] = acc[i][j][r] * alpha;
      }
  } else {
    const float* bias = sel == 0 ? bq : (sel == 1 ? bk : bv);
    if (sel == 2) {
      // V transposed: vT[(b*H + n)*S + t_pos], b = m>>11, t_pos = m&2047.
#pragma unroll
      for (int j = 0; j < 4; ++j) {
        const int n = ntile + wn + j * 16 + l16;
        const float bb = bias[n];
#pragma unroll
        for (int i = 0; i < 4; ++i) {
          const int m = mtile + wm + i * 16 + quad * 4;
          f16x4 pack;
#pragma unroll
          for (int r = 0; r < 4; ++r) pack[r] = (f16)(acc[i][j][r] + bb);
          *(f16x4*)&vT[((long)(m >> 11) * H_ + n) * S_ + (m & 2047)] = pack;
        }
      }
    } else {
      f16* C = (f16*)Cout + (long)sel * M_ * H_;
#pragma unroll
      for (int j = 0; j < 4; ++j) {
        const int n = ntile + wn + j * 16 + l16;
        const float bb = bias[n];
#pragma unroll
        for (int i = 0; i < 4; ++i) {
          const long m = mtile + wm + i * 16 + quad * 4;
#pragma unroll
          for (int r = 0; r < 4; ++r)
            C[(m + r) * ldc + n] = (f16)(acc[i][j][r] + bb);
        }
      }
    }
  }
}

// ---------------------------------------------------------------------------
// In-place row softmax over 2048 fp16 scores + quantize to fp16.
__global__ __launch_bounds__(256) void softmax_q(f16* __restrict__ sc) {
  const long row = blockIdx.x;
  f16* p = sc + row * S_;
  const int t = threadIdx.x;
  const int wave = t >> 6, lane = t & 63;
  f16x8 v = ((const f16x8*)p)[t];
  float f[8];
  float m = -3.0e38f;
#pragma unroll
  for (int c = 0; c < 8; c++) { f[c] = (float)v[c]; m = fmaxf(m, f[c]); }
#pragma unroll
  for (int o = 32; o > 0; o >>= 1) m = fmaxf(m, __shfl_xor(m, o));
  __shared__ float redm[4], reds[4];
  if (lane == 0) redm[wave] = m;
  __syncthreads();
  m = fmaxf(fmaxf(redm[0], redm[1]), fmaxf(redm[2], redm[3]));
  float s = 0.f, e[8];
#pragma unroll
  for (int c = 0; c < 8; c++) { e[c] = __expf(f[c] - m); s += e[c]; }
#pragma unroll
  for (int o = 32; o > 0; o >>= 1) s += __shfl_xor(s, o);
  if (lane == 0) reds[wave] = s;
  __syncthreads();
  s = reds[0] + reds[1] + reds[2] + reds[3];
  float inv = 1.0f / s;
  f16x8 ov;
#pragma unroll
  for (int c = 0; c < 8; c++) ov[c] = (f16)(e[c] * inv);
  ((f16x8*)p)[t] = ov;
}

// ---------------------------------------------------------------------------
extern "C" void kernel_launch(void* const* d_in, const int* in_sizes, int n_in,
                              void* d_out, int out_size, void* d_ws, size_t ws_size,
                              hipStream_t stream) {
  (void)in_sizes; (void)n_in; (void)out_size; (void)ws_size;
  const float* x  = (const float*)d_in[0];
  const float* Wq = (const float*)d_in[1];
  const float* bq = (const float*)d_in[2];
  const float* Wk = (const float*)d_in[3];
  const float* bk = (const float*)d_in[4];
  const float* Wv = (const float*)d_in[5];
  const float* bv = (const float*)d_in[6];

  char* ws = (char*)d_ws;
  f16* xh  = (f16*)ws; ws += (size_t)M_ * H_ * 2;          // 16 MiB
  f16* Wh  = (f16*)ws; ws += (size_t)3 * H_ * H_ * 2;      // 6 MiB
  f16* qkv = (f16*)ws; ws += (size_t)2 * M_ * H_ * 2;      // 32 MiB (q, k)
  f16* vT  = (f16*)ws; ws += (size_t)B_ * H_ * S_ * 2;     // 16 MiB
  f16* sc  = (f16*)ws; ws += (size_t)B_ * S_ * S_ * 2;     // 32 MiB (scores, then attn in-place)

  // 1) x, Wq/Wk/Wv -> fp16 in one launch
  downconvert_all<<<M_ * H_ / 1024 + 3 * H_ * H_ / 1024, 256, 0, stream>>>(
      x, Wq, Wk, Wv, xh, Wh);

  // 2) fused QKV projection + bias + quantize; V written transposed.
  //    grid 64 x 24 = 1536 blocks, 2/CU.
  gemm_d<1024, 2><<<dim3(64, 24), 256, 0, stream>>>(
      xh, Wh, qkv, vT, bq, bk, bv, H_, H_, H_, 0, 0, 0, 0.f);

  // 3) scores = quantize(q @ k^T / 32): grid 16 x 16 x 4 = 1024 blocks.
  gemm_d<1024, 0><<<dim3(16, 16, 4), 256, 0, stream>>>(
      qkv, qkv + (size_t)M_ * H_, sc, nullptr, nullptr, nullptr, nullptr,
      H_, H_, S_, (long)S_ * H_, (long)S_ * H_, (long)S_ * S_, 0.03125f);

  // 4) attn = quantize(softmax(scores)) in-place
  softmax_q<<<M_, 256, 0, stream>>>(sc);

  // 5) out = attn @ vT^T (fp32 straight to d_out): grid 16 x 8 x 4 = 512.
  gemm_d<2048, 1><<<dim3(16, 8, 4), 256, 0, stream>>>(
      sc, vT, d_out, nullptr, nullptr, nullptr, nullptr,
      S_, S_, H_, (long)S_ * S_, (long)H_ * S_, (long)S_ * H_, 1.0f);
}

// Round 6
// 243.727 us; speedup vs baseline: 1.0759x; 1.0387x over previous
//
#include <hip/hip_runtime.h>
#include <hip/hip_fp16.h>

#define B_ 4
#define S_ 2048
#define H_ 1024
#define M_ (B_ * S_)  // 8192 flattened rows of x / q / k / v

typedef _Float16 f16;
typedef _Float16 f16x8 __attribute__((ext_vector_type(8)));
typedef _Float16 f16x4 __attribute__((ext_vector_type(4)));
typedef float f32x4 __attribute__((ext_vector_type(4)));

typedef __attribute__((address_space(3))) unsigned int* lds_u32p;
typedef const __attribute__((address_space(1))) unsigned int* gbl_u32p;

// async global->LDS, 16B per lane; LDS dest is wave-uniform base + lane*16
__device__ __forceinline__ void stage16(const f16* g, f16* l) {
  __builtin_amdgcn_global_load_lds((gbl_u32p)g, (lds_u32p)l, 16, 0, 0);
}

// ---------------------------------------------------------------------------
// One launch: x (8192 blocks) then Wq/Wk/Wv (1024 blocks each) -> fp16 RNE.
__global__ __launch_bounds__(256) void downconvert_all(
    const float* __restrict__ x, const float* __restrict__ W0,
    const float* __restrict__ W1, const float* __restrict__ W2,
    f16* __restrict__ xh, f16* __restrict__ Wh) {
  const int b = blockIdx.x;
  const float* src;
  f16* dst;
  long i;
  if (b < M_ * H_ / 1024) {  // 8192 x-blocks
    src = x; dst = xh;
    i = (long)b * 256 + threadIdx.x;
  } else {
    const int wb = b - M_ * H_ / 1024;
    const int sel = wb >> 10;               // 1024 blocks per W
    src = sel == 0 ? W0 : (sel == 1 ? W1 : W2);
    dst = Wh + (long)sel * H_ * H_;
    i = (long)(wb & 1023) * 256 + threadIdx.x;
  }
  f32x4 v = ((const f32x4*)src)[i];
  f16x4 h;
#pragma unroll
  for (int c = 0; c < 4; c++) h[c] = (f16)v[c];
  ((f16x4*)dst)[i] = h;
}

// ---------------------------------------------------------------------------
// Fused QKV projection — round-0 structure VERBATIM (best measured: 61.5us)
// plus the r3/r5-verified chunk-XOR LDS swizzle (conflicts 6.29M -> 0):
// 16B chunk c of row r holds global chunk c ^ ((r>>1)&3); applied on the
// global SOURCE of stage16 (LDS dest linear) and on the ds_read address.
// NT GEMM, 128x128 tile, BK=64 as two BK=32 sub-chunks per barrier.
// sel==2 (V) is written TRANSPOSED to vT[b][h][t].
__global__ __launch_bounds__(256, 2)
void qkv_gemm(const f16* __restrict__ xh, const f16* __restrict__ Wh,
              const float* __restrict__ bq, const float* __restrict__ bk,
              const float* __restrict__ bv, f16* __restrict__ qkv,
              f16* __restrict__ vT) {
  __shared__ __align__(16) f16 As[2 * 128 * 32];  // [chunk0 | chunk1]
  __shared__ __align__(16) f16 Bs[2 * 128 * 32];
  const int t = threadIdx.x;
  const int wave = t >> 6, lane = t & 63;
  const int quad = lane >> 4, l16 = lane & 15;
  const int wm = (wave & 1) * 64, wn = (wave >> 1) * 64;
  const int sel = blockIdx.y >> 3;             // 0=q 1=k 2=v
  const int ntile = (blockIdx.y & 7) * 128;
  const int mtile = blockIdx.x * 128;

  const f16* Ab = xh + (long)mtile * H_;
  const f16* Bb = Wh + (long)sel * H_ * H_ + (long)ntile * H_;

  const int r0 = t >> 2;        // staging row 0..63
  // swizzled source chunk: (t&3) ^ ((row>>1)&3); same for row+64.
  const int c8 = ((t & 3) ^ ((r0 >> 1) & 3)) * 8;

  // ds_read swizzle: frag row = w?+i*16+l16 -> (row>>1)&3 == (l16>>1)&3
  const int swz8 = (quad ^ ((l16 >> 1) & 3)) * 8;

  f32x4 acc[4][4] = {};

  for (int k0 = 0; k0 < H_; k0 += 64) {
    __syncthreads();
    stage16(Ab + (long)r0 * H_ + k0 + c8,             As + t * 8);
    stage16(Ab + (long)(r0 + 64) * H_ + k0 + c8,      As + 2048 + t * 8);
    stage16(Ab + (long)r0 * H_ + k0 + 32 + c8,        As + 4096 + t * 8);
    stage16(Ab + (long)(r0 + 64) * H_ + k0 + 32 + c8, As + 6144 + t * 8);
    stage16(Bb + (long)r0 * H_ + k0 + c8,             Bs + t * 8);
    stage16(Bb + (long)(r0 + 64) * H_ + k0 + c8,      Bs + 2048 + t * 8);
    stage16(Bb + (long)r0 * H_ + k0 + 32 + c8,        Bs + 4096 + t * 8);
    stage16(Bb + (long)(r0 + 64) * H_ + k0 + 32 + c8, Bs + 6144 + t * 8);
    __syncthreads();
#pragma unroll
    for (int kk = 0; kk < 2; kk++) {
      f16x8 ah[4], bh[4];
#pragma unroll
      for (int i = 0; i < 4; i++) {
        ah[i] = *(const f16x8*)&As[kk * 4096 + (wm + i * 16 + l16) * 32 + swz8];
        bh[i] = *(const f16x8*)&Bs[kk * 4096 + (wn + i * 16 + l16) * 32 + swz8];
      }
#pragma unroll
      for (int i = 0; i < 4; i++)
#pragma unroll
        for (int j = 0; j < 4; j++)
          acc[i][j] = __builtin_amdgcn_mfma_f32_16x16x32_f16(ah[i], bh[j], acc[i][j], 0, 0, 0);
    }
  }

  const float* bias = sel == 0 ? bq : (sel == 1 ? bk : bv);
  if (sel == 2) {
    // V transposed: vT[(b*H + n)*S + t_pos], b = m>>11, t_pos = m&2047.
#pragma unroll
    for (int j = 0; j < 4; j++) {
      int n = ntile + wn + j * 16 + l16;
      float bb = bias[n];
#pragma unroll
      for (int i = 0; i < 4; i++) {
        int m = mtile + wm + i * 16 + quad * 4;
        f16x4 pack;
#pragma unroll
        for (int r = 0; r < 4; r++) pack[r] = (f16)(acc[i][j][r] + bb);
        *(f16x4*)&vT[((long)(m >> 11) * H_ + n) * S_ + (m & 2047)] = pack;
      }
    }
  } else {
    f16* out = qkv + (long)sel * M_ * H_;
#pragma unroll
    for (int j = 0; j < 4; j++) {
      int n = ntile + wn + j * 16 + l16;
      float bb = bias[n];
#pragma unroll
      for (int i = 0; i < 4; i++) {
        int m = mtile + wm + i * 16 + quad * 4;
#pragma unroll
        for (int r = 0; r < 4; r++)
          out[(long)(m + r) * H_ + n] = (f16)(acc[i][j][r] + bb);
      }
    }
  }
}

// ---------------------------------------------------------------------------
// Generic batched NT fp16 GEMM — round-0 structure + verified swizzle.
// C[z][m][n] = alpha * sum_k A[z][m][k]*B[z][n][k]
template <int OUT_F16>
__global__ __launch_bounds__(256, 2)
void gemm_nt(const f16* __restrict__ A, const f16* __restrict__ Bm,
             void* __restrict__ C, int lda, int ldb, int ldc, int K,
             long sA, long sB, long sC, float alpha) {
  __shared__ __align__(16) f16 As[2 * 128 * 32];
  __shared__ __align__(16) f16 Bs[2 * 128 * 32];
  const int t = threadIdx.x;
  const int wave = t >> 6, lane = t & 63;
  const int quad = lane >> 4, l16 = lane & 15;
  const int wm = (wave & 1) * 64, wn = (wave >> 1) * 64;
  const f16* Ab = A + blockIdx.z * sA + (long)blockIdx.x * 128 * lda;
  const f16* Bb = Bm + blockIdx.z * sB + (long)blockIdx.y * 128 * ldb;
  const int r0 = t >> 2;
  const int c8 = ((t & 3) ^ ((r0 >> 1) & 3)) * 8;
  const int swz8 = (quad ^ ((l16 >> 1) & 3)) * 8;
  f32x4 acc[4][4] = {};
  for (int k0 = 0; k0 < K; k0 += 64) {
    __syncthreads();
    stage16(Ab + (long)r0 * lda + k0 + c8,             As + t * 8);
    stage16(Ab + (long)(r0 + 64) * lda + k0 + c8,      As + 2048 + t * 8);
    stage16(Ab + (long)r0 * lda + k0 + 32 + c8,        As + 4096 + t * 8);
    stage16(Ab + (long)(r0 + 64) * lda + k0 + 32 + c8, As + 6144 + t * 8);
    stage16(Bb + (long)r0 * ldb + k0 + c8,             Bs + t * 8);
    stage16(Bb + (long)(r0 + 64) * ldb + k0 + c8,      Bs + 2048 + t * 8);
    stage16(Bb + (long)r0 * ldb + k0 + 32 + c8,        Bs + 4096 + t * 8);
    stage16(Bb + (long)(r0 + 64) * ldb + k0 + 32 + c8, Bs + 6144 + t * 8);
    __syncthreads();
#pragma unroll
    for (int kk = 0; kk < 2; kk++) {
      f16x8 af[4], bf[4];
#pragma unroll
      for (int i = 0; i < 4; i++) {
        af[i] = *(const f16x8*)&As[kk * 4096 + (wm + i * 16 + l16) * 32 + swz8];
        bf[i] = *(const f16x8*)&Bs[kk * 4096 + (wn + i * 16 + l16) * 32 + swz8];
      }
#pragma unroll
      for (int i = 0; i < 4; i++)
#pragma unroll
        for (int j = 0; j < 4; j++)
          acc[i][j] = __builtin_amdgcn_mfma_f32_16x16x32_f16(af[i], bf[j], acc[i][j], 0, 0, 0);
    }
  }
  const long mb = (long)blockIdx.x * 128 + wm;
  const long nb = (long)blockIdx.y * 128 + wn;
#pragma unroll
  for (int i = 0; i < 4; i++)
#pragma unroll
    for (int j = 0; j < 4; j++) {
      long m = mb + i * 16 + quad * 4;
      long n = nb + j * 16 + l16;
#pragma unroll
      for (int r = 0; r < 4; r++) {
        float v = acc[i][j][r] * alpha;
        if (OUT_F16)
          ((f16*)C)[blockIdx.z * sC + (m + r) * ldc + n] = (f16)v;
        else
          ((float*)C)[blockIdx.z * sC + (m + r) * ldc + n] = v;
      }
    }
}

// ---------------------------------------------------------------------------
// Wave-per-row softmax + fp16 quantize: 4 rows per 256-thread block.
// No LDS, no __syncthreads, pure shfl reductions; 64B/lane vectorized I/O.
__global__ __launch_bounds__(256) void softmax_w(f16* __restrict__ sc) {
  const int wave = threadIdx.x >> 6, lane = threadIdx.x & 63;
  const long row = (long)blockIdx.x * 4 + wave;
  f16* p = sc + row * S_;
  f16x8 v[4];
#pragma unroll
  for (int i = 0; i < 4; ++i) v[i] = ((const f16x8*)p)[i * 64 + lane];
  float f[32];
  float m = -3.0e38f;
#pragma unroll
  for (int i = 0; i < 4; ++i)
#pragma unroll
    for (int c = 0; c < 8; ++c) {
      float x = (float)v[i][c];
      f[i * 8 + c] = x;
      m = fmaxf(m, x);
    }
#pragma unroll
  for (int o = 32; o > 0; o >>= 1) m = fmaxf(m, __shfl_xor(m, o));
  float s = 0.f;
#pragma unroll
  for (int i = 0; i < 32; ++i) { f[i] = __expf(f[i] - m); s += f[i]; }
#pragma unroll
  for (int o = 32; o > 0; o >>= 1) s += __shfl_xor(s, o);
  const float inv = 1.0f / s;
#pragma unroll
  for (int i = 0; i < 4; ++i) {
    f16x8 ov;
#pragma unroll
    for (int c = 0; c < 8; ++c) ov[c] = (f16)(f[i * 8 + c] * inv);
    ((f16x8*)p)[i * 64 + lane] = ov;
  }
}

// ---------------------------------------------------------------------------
extern "C" void kernel_launch(void* const* d_in, const int* in_sizes, int n_in,
                              void* d_out, int out_size, void* d_ws, size_t ws_size,
                              hipStream_t stream) {
  (void)in_sizes; (void)n_in; (void)out_size; (void)ws_size;
  const float* x  = (const float*)d_in[0];
  const float* Wq = (const float*)d_in[1];
  const float* bq = (const float*)d_in[2];
  const float* Wk = (const float*)d_in[3];
  const float* bk = (const float*)d_in[4];
  const float* Wv = (const float*)d_in[5];
  const float* bv = (const float*)d_in[6];

  char* ws = (char*)d_ws;
  f16* xh  = (f16*)ws; ws += (size_t)M_ * H_ * 2;          // 16 MiB
  f16* Wh  = (f16*)ws; ws += (size_t)3 * H_ * H_ * 2;      // 6 MiB
  f16* qkv = (f16*)ws; ws += (size_t)2 * M_ * H_ * 2;      // 32 MiB (q, k)
  f16* vT  = (f16*)ws; ws += (size_t)B_ * H_ * S_ * 2;     // 16 MiB
  f16* sc  = (f16*)ws; ws += (size_t)B_ * S_ * S_ * 2;     // 32 MiB (scores, then attn in-place)

  // 1) x, Wq/Wk/Wv -> fp16 in one launch
  downconvert_all<<<M_ * H_ / 1024 + 3 * H_ * H_ / 1024, 256, 0, stream>>>(
      x, Wq, Wk, Wv, xh, Wh);

  // 2) fused QKV projection + bias + quantize; V written transposed
  qkv_gemm<<<dim3(64, 24), 256, 0, stream>>>(xh, Wh, bq, bk, bv, qkv, vT);

  // 3) scores = quantize(q @ k^T / 32), per batch
  gemm_nt<1><<<dim3(16, 16, 4), 256, 0, stream>>>(
      qkv, qkv + (size_t)M_ * H_, sc, H_, H_, S_, H_,
      (long)S_ * H_, (long)S_ * H_, (long)S_ * S_, 0.03125f);

  // 4) attn = quantize(softmax(scores)) in-place — wave-per-row, no barriers
  softmax_w<<<M_ / 4, 256, 0, stream>>>(sc);

  // 5) out = attn @ vT^T  (fp32 epilogue straight to d_out)
  gemm_nt<0><<<dim3(16, 8, 4), 256, 0, stream>>>(
      sc, vT, d_out, S_, S_, H_, S_,
      (long)S_ * S_, (long)H_ * S_, (long)S_ * H_, 1.0f);
}